// Round 5
// baseline (192.340 us; speedup 1.0000x reference)
//
#include <hip/hip_runtime.h>
#include <hip/hip_bf16.h>
#include <stdint.h>

#define KDIM 4096
#define BM 64
#define BN 128
#define BK 64
#define NT (KDIM / BK)   // 64 K-steps

typedef __attribute__((ext_vector_type(8))) short bf16x8;
typedef __attribute__((ext_vector_type(4))) float f32x4;

__device__ inline unsigned short f2bf_bits(float f) {
  union { __hip_bfloat16 h; unsigned short u; } cv;
  cv.h = __float2bfloat16(f);
  return cv.u;
}

// Replicates: scaled = t / bm * 6; q = sign * nearest_palette(|scaled|) (ties -> lower);
// dq = q * (bm/6), rounded to bf16. Division kept exact (fp32 div) so palette
// boundary decisions bit-match the reference.
__device__ inline unsigned short qdq(float t, float bm, float scale) {
  float s = t / bm;
  s = s * 6.0f;
  float a = fabsf(s);
  float v;
  if (a <= 0.25f)      v = 0.0f;
  else if (a <= 0.75f) v = 0.5f;
  else if (a <= 1.25f) v = 1.0f;
  else if (a <= 1.75f) v = 1.5f;
  else if (a <= 2.5f)  v = 2.0f;
  else if (a <= 3.5f)  v = 3.0f;
  else if (a <= 5.0f)  v = 4.0f;
  else                 v = 6.0f;
  float q = copysignf(v, s);
  return f2bf_bits(q * scale);
}

// Fused quant+dequant for both tensors. One 8-lane subgroup = one 32-elem block.
__global__ void nvfp4_quant_dq2(const float* __restrict__ x, unsigned short* __restrict__ xq,
                                int nsub_x,
                                const float* __restrict__ w, unsigned short* __restrict__ wq,
                                int nsub_total) {
  int gid = blockIdx.x * blockDim.x + threadIdx.x;
  int sub = gid >> 3;
  if (sub >= nsub_total) return;
  const float* in;
  unsigned short* out;
  if (sub < nsub_x) { in = x; out = xq; }
  else { in = w; out = wq; sub -= nsub_x; }
  int l8 = gid & 7;
  long base = (long)sub * 32 + (long)l8 * 4;
  const float4 v = *(const float4*)(in + base);
  float amax = fmaxf(fmaxf(fabsf(v.x), fabsf(v.y)), fmaxf(fabsf(v.z), fabsf(v.w)));
  amax = fmaxf(amax, __shfl_xor(amax, 1));
  amax = fmaxf(amax, __shfl_xor(amax, 2));
  amax = fmaxf(amax, __shfl_xor(amax, 4));
  float bm = fmaxf(amax, 1e-12f);   // jnp.clip(max, 1e-12)
  float scale = bm / 6.0f;
  ushort4 o;
  o.x = qdq(v.x, bm, scale);
  o.y = qdq(v.y, bm, scale);
  o.z = qdq(v.z, bm, scale);
  o.w = qdq(v.w, bm, scale);
  *(ushort4*)(out + base) = o;
}

// C[M,N] = A[M,K](bf16) * B[N,K]^T(bf16).
// 64x128 tile, BK=64, 4 waves (2x2), each wave 32x64 via 2x4 grid of 16x16x32 MFMA.
// R5: A-operand loaded DIRECTLY global->VGPR fragments (L2-resident panels; LDS
// reuse for A was only 2x, not worth the bandwidth). B double-buffered in 32 KB LDS
// with chunk-XOR swizzle on global source + ds_read addr (conflicts = 0, R1-proven).
// Counted vmcnt (never 0 in loop), raw s_barriers, 2x-unrolled loop with named
// A-fragment ping-pong sets. Grid = 512 blocks = 2 blocks/CU.
__global__ __launch_bounds__(256, 2) void gemm_bf16_bt(
    const unsigned short* __restrict__ A,  // [M, K]
    const unsigned short* __restrict__ B,  // [N, K]
    float* __restrict__ C, int M, int N) {
  __shared__ unsigned short Bs[2][BN * BK];   // 2 x 16 KB

  const int tid = threadIdx.x;
  const int wave = tid >> 6;
  const int lane = tid & 63;
  const int wm = wave >> 1;       // 0..1  (32-row half)
  const int wn = wave & 1;        // 0..1  (64-col half)
  const int quad = lane >> 4;     // 0..3
  const int r16 = lane & 15;      // 0..15

  const int nbx = N / BN;
  const int nby = M / BM;
  int bx, by;
  {
    int bid = blockIdx.x;
    if (nbx == 32 && nby == 16) {
      // XCD-chunked swizzle (512 = 8 XCD x 64, bijective): XCD x owns bx in
      // [4x, 4x+4) — B-panels XCD-private in L2; consecutive c share by -> A-panel
      // L2/L1-resident for the direct A-fragment loads.
      int xcd = bid & 7;
      int c = bid >> 3;            // 0..63
      bx = xcd * 4 + (c & 3);
      by = c >> 2;                 // 0..15
    } else {
      bx = bid % nbx;
      by = bid / nbx;
    }
  }
  const int bm0 = by * BM;
  const int bn0 = bx * BN;

  // ---- B staging map: 128 rows x 8 chunks of 16B = 1024 slots, 4/thread.
  // LDS slot (row, ch) receives GLOBAL chunk (ch ^ (row&7)) [inverse-swizzled
  // source, linear LDS dest -> swizzled ds_read gets global chunk c conflict-free].
  const unsigned short* gB[4];
  int offB[4];
#pragma unroll
  for (int s = 0; s < 4; s++) {
    int slot = s * 256 + tid;        // 0..1023
    int row = slot >> 3;             // 0..127
    int ch = slot & 7;
    int sch = ch ^ (row & 7);
    gB[s] = B + (long)(bn0 + row) * KDIM + sch * 8;
    offB[s] = slot * 8;
  }

  // ---- B fragment read offsets (shorts), chunk-XOR swizzled
  int boff[2][4];
#pragma unroll
  for (int kk = 0; kk < 2; kk++) {
#pragma unroll
    for (int j = 0; j < 4; j++) {
      int br = wn * 64 + j * 16 + r16;
      boff[kk][j] = br * BK + (((kk * 4 + quad) ^ (br & 7)) * 8);
    }
  }

  // ---- A direct-load bases: row = bm0 + wm*32 + i*16 + r16, k = t*BK + kk*32 + quad*8
  const unsigned short* aBase[2];
#pragma unroll
  for (int i = 0; i < 2; i++)
    aBase[i] = A + (long)(bm0 + wm * 32 + i * 16 + r16) * KDIM + quad * 8;

  f32x4 acc[2][4] = {};
  bf16x8 aA[2][2], aB_[2][2];   // ping-pong A fragment sets [i][kk]

  unsigned short *sb0 = Bs[0], *sb1 = Bs[1];

#define AFRAG_LOAD(DST, T)                                                          \
  do {                                                                              \
    _Pragma("unroll") for (int i = 0; i < 2; i++)                                   \
      _Pragma("unroll") for (int kk = 0; kk < 2; kk++)                              \
        DST[i][kk] = *(const bf16x8*)(aBase[i] + (long)(T) * BK + kk * 32);         \
  } while (0)

#define STAGE_B(SB, T)                                                              \
  do {                                                                              \
    _Pragma("unroll") for (int s = 0; s < 4; s++)                                   \
      __builtin_amdgcn_global_load_lds(                                             \
          (const __attribute__((address_space(1))) void*)(gB[s] + (long)(T) * BK),  \
          (__attribute__((address_space(3))) void*)((SB) + offB[s]), 16, 0, 0);     \
  } while (0)

#define COMPUTE_R(AF, SB)                                                           \
  do {                                                                              \
    _Pragma("unroll") for (int kk = 0; kk < 2; kk++) {                              \
      bf16x8 bfr[4];                                                                \
      _Pragma("unroll") for (int j = 0; j < 4; j++)                                 \
        bfr[j] = *(const bf16x8*)((SB) + boff[kk][j]);                              \
      _Pragma("unroll") for (int i = 0; i < 2; i++)                                 \
        _Pragma("unroll") for (int j = 0; j < 4; j++)                               \
          acc[i][j] =                                                               \
              __builtin_amdgcn_mfma_f32_16x16x32_bf16(AF[i][kk], bfr[j],            \
                                                      acc[i][j], 0, 0, 0);          \
    }                                                                               \
  } while (0)

  // ---- prologue: A(0) + B(0) + B(1) in flight (12); vmcnt(4) retires A(0), B(0).
  AFRAG_LOAD(aA, 0);
  STAGE_B(sb0, 0);
  STAGE_B(sb1, 1);
  asm volatile("s_waitcnt vmcnt(4)" ::: "memory");
  __builtin_amdgcn_s_barrier();
  __builtin_amdgcn_sched_barrier(0);

  // Steady-state vmcnt FIFO (per thread, oldest->newest): [B(t+1) 4, A(t+1) 4]
  // at each iteration entry. STAGE adds 4 -> vmcnt(8) retires exactly B(t+1).
#pragma unroll 1
  for (int t = 0; t < NT - 2; t += 2) {
    // --- iter t: compute A=aA, B tile t in sb0
    AFRAG_LOAD(aB_, t + 1);
    COMPUTE_R(aA, sb0);                                  // compiler waits aA precisely
    asm volatile("s_waitcnt lgkmcnt(0)" ::: "memory");   // sb0 readers done
    __builtin_amdgcn_s_barrier();
    __builtin_amdgcn_sched_barrier(0);
    STAGE_B(sb0, t + 2);
    asm volatile("s_waitcnt vmcnt(8)" ::: "memory");     // B(t+1) landed
    __builtin_amdgcn_s_barrier();
    __builtin_amdgcn_sched_barrier(0);
    // --- iter t+1: compute A=aB_, B tile t+1 in sb1
    AFRAG_LOAD(aA, t + 2);
    COMPUTE_R(aB_, sb1);
    asm volatile("s_waitcnt lgkmcnt(0)" ::: "memory");   // sb1 readers done
    __builtin_amdgcn_s_barrier();
    __builtin_amdgcn_sched_barrier(0);
    STAGE_B(sb1, t + 3);                                 // t+3 <= NT-1 for t <= NT-4
    asm volatile("s_waitcnt vmcnt(8)" ::: "memory");     // B(t+2) landed
    __builtin_amdgcn_s_barrier();
    __builtin_amdgcn_sched_barrier(0);
  }

  // ---- tail: tile NT-2 (in sb0, A in aA), tile NT-1 (in sb1, A loaded now)
  AFRAG_LOAD(aB_, NT - 1);
  COMPUTE_R(aA, sb0);
  asm volatile("s_waitcnt vmcnt(4)" ::: "memory");       // B(NT-1) landed
  __builtin_amdgcn_s_barrier();
  __builtin_amdgcn_sched_barrier(0);
  COMPUTE_R(aB_, sb1);                                   // compiler waits aB_

#undef AFRAG_LOAD
#undef STAGE_B
#undef COMPUTE_R

  // Epilogue: C/D layout col = lane&15, row = quad*4 + reg
#pragma unroll
  for (int i = 0; i < 2; i++) {
#pragma unroll
    for (int j = 0; j < 4; j++) {
      const int row = bm0 + wm * 32 + i * 16 + quad * 4;
      const int col = bn0 + wn * 64 + j * 16 + r16;
#pragma unroll
      for (int r = 0; r < 4; r++)
        C[(long)(row + r) * N + col] = acc[i][j][r];
    }
  }
}

extern "C" void kernel_launch(void* const* d_in, const int* in_sizes, int n_in,
                              void* d_out, int out_size, void* d_ws, size_t ws_size,
                              hipStream_t stream) {
  const float* x = (const float*)d_in[0];   // [M, K] fp32
  const float* w = (const float*)d_in[1];   // [N, K] fp32
  float* out = (float*)d_out;               // [M, N] fp32

  const int MK = in_sizes[0];
  const int NK = in_sizes[1];
  const int M = MK / KDIM;
  const int N = NK / KDIM;

  unsigned short* xq = (unsigned short*)d_ws;        // [M, K] bf16
  unsigned short* wq = xq + (size_t)MK;              // [N, K] bf16

  const int nsub_x = MK / 32;
  const int nsub_total = nsub_x + NK / 32;
  nvfp4_quant_dq2<<<dim3((nsub_total * 8 + 255) / 256), dim3(256), 0, stream>>>(
      x, xq, nsub_x, w, wq, nsub_total);

  dim3 grid((N / BN) * (M / BM));
  gemm_bf16_bt<<<grid, dim3(256), 0, stream>>>(xq, wq, out, M, N);
}

// Round 6
// 171.204 us; speedup vs baseline: 1.1235x; 1.1235x over previous
//
#include <hip/hip_runtime.h>
#include <hip/hip_bf16.h>
#include <stdint.h>

#define KDIM 4096
#define BM 64
#define BN 128
#define BK 64
#define NT (KDIM / BK)   // 64 K-steps

typedef __attribute__((ext_vector_type(8))) short bf16x8;
typedef __attribute__((ext_vector_type(4))) float f32x4;

__device__ inline unsigned short f2bf_bits(float f) {
  union { __hip_bfloat16 h; unsigned short u; } cv;
  cv.h = __float2bfloat16(f);
  return cv.u;
}

// Replicates: scaled = t / bm * 6; q = sign * nearest_palette(|scaled|) (ties -> lower);
// dq = q * (bm/6), rounded to bf16. Division kept exact (fp32 div) so palette
// boundary decisions bit-match the reference.
__device__ inline unsigned short qdq(float t, float bm, float scale) {
  float s = t / bm;
  s = s * 6.0f;
  float a = fabsf(s);
  float v;
  if (a <= 0.25f)      v = 0.0f;
  else if (a <= 0.75f) v = 0.5f;
  else if (a <= 1.25f) v = 1.0f;
  else if (a <= 1.75f) v = 1.5f;
  else if (a <= 2.5f)  v = 2.0f;
  else if (a <= 3.5f)  v = 3.0f;
  else if (a <= 5.0f)  v = 4.0f;
  else                 v = 6.0f;
  float q = copysignf(v, s);
  return f2bf_bits(q * scale);
}

// Fused quant+dequant for both tensors. One 8-lane subgroup = one 32-elem block.
__global__ void nvfp4_quant_dq2(const float* __restrict__ x, unsigned short* __restrict__ xq,
                                int nsub_x,
                                const float* __restrict__ w, unsigned short* __restrict__ wq,
                                int nsub_total) {
  int gid = blockIdx.x * blockDim.x + threadIdx.x;
  int sub = gid >> 3;
  if (sub >= nsub_total) return;
  const float* in;
  unsigned short* out;
  if (sub < nsub_x) { in = x; out = xq; }
  else { in = w; out = wq; sub -= nsub_x; }
  int l8 = gid & 7;
  long base = (long)sub * 32 + (long)l8 * 4;
  const float4 v = *(const float4*)(in + base);
  float amax = fmaxf(fmaxf(fabsf(v.x), fabsf(v.y)), fmaxf(fabsf(v.z), fabsf(v.w)));
  amax = fmaxf(amax, __shfl_xor(amax, 1));
  amax = fmaxf(amax, __shfl_xor(amax, 2));
  amax = fmaxf(amax, __shfl_xor(amax, 4));
  float bm = fmaxf(amax, 1e-12f);   // jnp.clip(max, 1e-12)
  float scale = bm / 6.0f;
  ushort4 o;
  o.x = qdq(v.x, bm, scale);
  o.y = qdq(v.y, bm, scale);
  o.z = qdq(v.z, bm, scale);
  o.w = qdq(v.w, bm, scale);
  *(ushort4*)(out + base) = o;
}

// C[M,N] = A[M,K](bf16) * B[N,K]^T(bf16).
// 64x128 tile, BK=64, 4 waves (2x2), each wave 32x64 via 2x4 grid of 16x16x32 MFMA.
// R6 = R4 (59us) + DEPTH-3 LDS pipeline: triple-buffered A+B (72 KB), STAGE(t+2)
// issued before COMPUTE(t), vmcnt(6) retires tile t+1 (issued TWO compute phases
// earlier -> load latency covered; R4's vmcnt wait was only 1 phase deep = stall).
// R5 lesson: A stays in LDS via global_load_lds (direct A-frag loads regressed 42%).
// Chunk-XOR swizzle on global source + ds_read addr (conflicts = 0). Raw barriers,
// never vmcnt(0) in loop. Grid = 512 blocks = 2 blocks/CU (144 KB LDS/CU fits).
__global__ __launch_bounds__(256, 2) void gemm_bf16_bt(
    const unsigned short* __restrict__ A,  // [M, K]
    const unsigned short* __restrict__ B,  // [N, K]
    float* __restrict__ C, int M, int N) {
  __shared__ unsigned short As[3][BM * BK];   // 3 x 8 KB
  __shared__ unsigned short Bs[3][BN * BK];   // 3 x 16 KB  (72 KB total)

  const int tid = threadIdx.x;
  const int wave = tid >> 6;
  const int lane = tid & 63;
  const int wm = wave >> 1;       // 0..1  (32-row half)
  const int wn = wave & 1;        // 0..1  (64-col half)
  const int quad = lane >> 4;     // 0..3
  const int r16 = lane & 15;      // 0..15

  const int nbx = N / BN;
  const int nby = M / BM;
  int bx, by;
  {
    int bid = blockIdx.x;
    if (nbx == 32 && nby == 16) {
      // XCD-chunked swizzle (512 = 8 XCD x 64, bijective): XCD x owns bx in
      // [4x, 4x+4) — B-panels XCD-private in L2 (read 16x, fetched once);
      // consecutive c share by -> A-panel L2-resident while B streams.
      int xcd = bid & 7;
      int c = bid >> 3;            // 0..63
      bx = xcd * 4 + (c & 3);
      by = c >> 2;                 // 0..15
    } else {
      bx = bid % nbx;
      by = bid / nbx;
    }
  }
  const int bm0 = by * BM;
  const int bn0 = bx * BN;

  // ---- staging map: rows x 8 chunks of 16B. A: 512 slots (2/thread),
  // B: 1024 slots (4/thread). LDS slot (row, ch) receives GLOBAL chunk
  // (ch ^ (row&7)) [inverse-swizzled source, linear LDS dest].
  const unsigned short* gA[2];
  const unsigned short* gB[4];
  int offA[2], offB[4];
#pragma unroll
  for (int s = 0; s < 2; s++) {
    int slot = s * 256 + tid;        // 0..511
    int row = slot >> 3;             // 0..63
    int ch = slot & 7;
    int sch = ch ^ (row & 7);
    gA[s] = A + (long)(bm0 + row) * KDIM + sch * 8;
    offA[s] = slot * 8;
  }
#pragma unroll
  for (int s = 0; s < 4; s++) {
    int slot = s * 256 + tid;        // 0..1023
    int row = slot >> 3;             // 0..127
    int ch = slot & 7;
    int sch = ch ^ (row & 7);
    gB[s] = B + (long)(bn0 + row) * KDIM + sch * 8;
    offB[s] = slot * 8;
  }

  // ---- fragment read offsets (shorts), chunk-XOR swizzled
  int aoff[2][2], boff[2][4];
#pragma unroll
  for (int kk = 0; kk < 2; kk++) {
#pragma unroll
    for (int i = 0; i < 2; i++) {
      int ar = wm * 32 + i * 16 + r16;
      aoff[kk][i] = ar * BK + (((kk * 4 + quad) ^ (ar & 7)) * 8);
    }
#pragma unroll
    for (int j = 0; j < 4; j++) {
      int br = wn * 64 + j * 16 + r16;
      boff[kk][j] = br * BK + (((kk * 4 + quad) ^ (br & 7)) * 8);
    }
  }

  f32x4 acc[2][4] = {};

  unsigned short *sa0 = As[0], *sa1 = As[1], *sa2 = As[2];
  unsigned short *sb0 = Bs[0], *sb1 = Bs[1], *sb2 = Bs[2];

#define STAGE(SA, SB, T)                                                            \
  do {                                                                              \
    _Pragma("unroll") for (int s = 0; s < 2; s++)                                   \
      __builtin_amdgcn_global_load_lds(                                             \
          (const __attribute__((address_space(1))) void*)(gA[s] + (long)(T) * BK),  \
          (__attribute__((address_space(3))) void*)((SA) + offA[s]), 16, 0, 0);     \
    _Pragma("unroll") for (int s = 0; s < 4; s++)                                   \
      __builtin_amdgcn_global_load_lds(                                             \
          (const __attribute__((address_space(1))) void*)(gB[s] + (long)(T) * BK),  \
          (__attribute__((address_space(3))) void*)((SB) + offB[s]), 16, 0, 0);     \
  } while (0)

#define COMPUTE(SA, SB)                                                             \
  do {                                                                              \
    _Pragma("unroll") for (int kk = 0; kk < 2; kk++) {                              \
      bf16x8 af[2], bfr[4];                                                         \
      _Pragma("unroll") for (int i = 0; i < 2; i++)                                 \
        af[i] = *(const bf16x8*)((SA) + aoff[kk][i]);                               \
      _Pragma("unroll") for (int j = 0; j < 4; j++)                                 \
        bfr[j] = *(const bf16x8*)((SB) + boff[kk][j]);                              \
      _Pragma("unroll") for (int i = 0; i < 2; i++)                                 \
        _Pragma("unroll") for (int j = 0; j < 4; j++)                               \
          acc[i][j] =                                                               \
              __builtin_amdgcn_mfma_f32_16x16x32_bf16(af[i], bfr[j], acc[i][j],     \
                                                      0, 0, 0);                     \
    }                                                                               \
  } while (0)

  // ---- prologue: tiles 0,1 in flight (12 outstanding); vmcnt(6) retires tile 0.
  STAGE(sa0, sb0, 0);
  STAGE(sa1, sb1, 1);
  asm volatile("s_waitcnt vmcnt(6)" ::: "memory");
  __builtin_amdgcn_s_barrier();
  __builtin_amdgcn_sched_barrier(0);

  // Steady state at loop entry: 6 outstanding (tile t+1). STAGE(t+2) -> 12.
  // vmcnt(6) after COMPUTE(t) retires tile t+1 — issued 2 compute phases ago.
#pragma unroll 1
  for (int t = 0; t < NT; t++) {
    if (t + 2 < NT) STAGE(sa2, sb2, t + 2);   // overwrites buf of tile t-1 (readers
                                              // drained at end-of-(t-1) lgkm+barrier)
    COMPUTE(sa0, sb0);
    if (t == NT - 1) break;
    asm volatile("s_waitcnt lgkmcnt(0)" ::: "memory");   // this wave's reads of buf t done
    __builtin_amdgcn_s_barrier();                        // all waves done reading buf t
    __builtin_amdgcn_sched_barrier(0);
    if (t + 2 < NT) {
      asm volatile("s_waitcnt vmcnt(6)" ::: "memory");   // tile t+1 landed
    } else {
      asm volatile("s_waitcnt vmcnt(0)" ::: "memory");   // last tile landed
    }
    __builtin_amdgcn_s_barrier();                        // tile t+1 visible block-wide
    __builtin_amdgcn_sched_barrier(0);
    unsigned short* tmp;
    tmp = sa0; sa0 = sa1; sa1 = sa2; sa2 = tmp;
    tmp = sb0; sb0 = sb1; sb1 = sb2; sb2 = tmp;
  }

#undef STAGE
#undef COMPUTE

  // Epilogue: C/D layout col = lane&15, row = quad*4 + reg
#pragma unroll
  for (int i = 0; i < 2; i++) {
#pragma unroll
    for (int j = 0; j < 4; j++) {
      const int row = bm0 + wm * 32 + i * 16 + quad * 4;
      const int col = bn0 + wn * 64 + j * 16 + r16;
#pragma unroll
      for (int r = 0; r < 4; r++)
        C[(long)(row + r) * N + col] = acc[i][j][r];
    }
  }
}

extern "C" void kernel_launch(void* const* d_in, const int* in_sizes, int n_in,
                              void* d_out, int out_size, void* d_ws, size_t ws_size,
                              hipStream_t stream) {
  const float* x = (const float*)d_in[0];   // [M, K] fp32
  const float* w = (const float*)d_in[1];   // [N, K] fp32
  float* out = (float*)d_out;               // [M, N] fp32

  const int MK = in_sizes[0];
  const int NK = in_sizes[1];
  const int M = MK / KDIM;
  const int N = NK / KDIM;

  unsigned short* xq = (unsigned short*)d_ws;        // [M, K] bf16
  unsigned short* wq = xq + (size_t)MK;              // [N, K] bf16

  const int nsub_x = MK / 32;
  const int nsub_total = nsub_x + NK / 32;
  nvfp4_quant_dq2<<<dim3((nsub_total * 8 + 255) / 256), dim3(256), 0, stream>>>(
      x, xq, nsub_x, w, wq, nsub_total);

  dim3 grid((N / BN) * (M / BM));
  gemm_bf16_bt<<<grid, dim3(256), 0, stream>>>(xq, wq, out, M, N);
}